// Round 1
// baseline (1529.244 us; speedup 1.0000x reference)
//
#include <hip/hip_runtime.h>

// Sinkhorn-Knopp, factored form: s_ij stays a_ij * u_i * v_j throughout.
// One 1024-thread block per batch element; the 512x512 fp32 matrix lives in
// registers (a[16][16] per thread, 256 elements). Thread (tr=tid&31, tc=tid>>5)
// owns rows {tr+32k} (strided => row mod 32 == lane => conflict-free LDS
// scatter) and cols [16*tc, 16*tc+16) (contiguous => 64B/row global loads).
#define MM 512
#define NN 512
#define NITER 20
#define SEPS 1e-10f

__global__ __launch_bounds__(1024) void sinkhorn_kernel(
    const float* __restrict__ s, const int* __restrict__ nrows,
    const int* __restrict__ ncols, float* __restrict__ out)
{
    __shared__ float sh_u[512];
    __shared__ float sh_v[512];
    __shared__ float red[16][513];   // +1 pad: stride 513 => bank = (h + idx) % 32

    const int b   = blockIdx.x;
    const int tid = threadIdx.x;
    const int tr  = tid & 31;        // row lane: owns rows tr + 32k
    const int tc  = tid >> 5;        // col tile: owns cols [16*tc, 16*tc+16)
    const int c0  = tc * 16;

    const int nr = nrows[b];
    const int nc = ncols[b];

    if (tid < 512) sh_u[tid] = 1.0f;

    // ---- load + mask: a = (r<nr && c<nc) ? s0 + EPS : 0 ----
    float a[16][16];
    const float* sb = s + (size_t)b * (MM * NN);
    #pragma unroll
    for (int k = 0; k < 16; ++k) {
        const int r = tr + 32 * k;
        const bool rv = (r < nr);
        const float4* rp = (const float4*)(sb + (size_t)r * NN + c0);
        #pragma unroll
        for (int q = 0; q < 4; ++q) {
            float4 val = rp[q];
            a[k][4*q+0] = (rv && (c0 + 4*q + 0) < nc) ? val.x + SEPS : 0.0f;
            a[k][4*q+1] = (rv && (c0 + 4*q + 1) < nc) ? val.y + SEPS : 0.0f;
            a[k][4*q+2] = (rv && (c0 + 4*q + 2) < nc) ? val.z + SEPS : 0.0f;
            a[k][4*q+3] = (rv && (c0 + 4*q + 3) < nc) ? val.w + SEPS : 0.0f;
        }
    }
    __syncthreads();   // sh_u init visible

    #pragma unroll 1
    for (int it = 0; it < NITER / 2; ++it) {
        // ---- even iter: column sums c_j = sum_i a_ij * u_i ; v_j = 1/c_j ----
        {
            float ur[16];
            #pragma unroll
            for (int k = 0; k < 16; ++k) ur[k] = sh_u[tr + 32*k];  // broadcast pairs
            #pragma unroll
            for (int j = 0; j < 16; ++j) {
                float acc = 0.0f;
                #pragma unroll
                for (int k = 0; k < 16; ++k) acc += a[k][j] * ur[k];
                acc += __shfl_xor(acc, 16);            // combine rows tr, tr+16
                if ((tid & 16) == 0) red[tr & 15][c0 + j] = acc;  // conflict-free
            }
        }
        __syncthreads();
        if (tid < 512) {
            float ssum = 0.0f;
            #pragma unroll
            for (int h = 0; h < 16; ++h) ssum += red[h][tid];
            sh_v[tid] = (ssum > 0.0f) ? 1.0f / ssum : 1.0f;
        }
        __syncthreads();

        // ---- odd iter: row sums r_i = sum_j a_ij * v_j ; u_i = 1/r_i ----
        {
            float vr[16];
            #pragma unroll
            for (int q = 0; q < 4; ++q) {
                float4 v4 = *(const float4*)&sh_v[c0 + 4*q];   // broadcast read
                vr[4*q+0] = v4.x; vr[4*q+1] = v4.y;
                vr[4*q+2] = v4.z; vr[4*q+3] = v4.w;
            }
            #pragma unroll
            for (int k = 0; k < 16; ++k) {
                float acc = 0.0f;
                #pragma unroll
                for (int j = 0; j < 16; ++j) acc += a[k][j] * vr[j];
                acc += __shfl_xor(acc, 32);            // combine col tiles tc, tc^1
                if ((tid & 32) == 0) red[tc >> 1][tr + 32*k] = acc;  // conflict-free
            }
        }
        __syncthreads();
        if (tid < 512) {
            float ssum = 0.0f;
            #pragma unroll
            for (int h = 0; h < 16; ++h) ssum += red[h][tid];
            sh_u[tid] = (ssum > 0.0f) ? 1.0f / ssum : 1.0f;
        }
        __syncthreads();
    }

    // ---- epilogue: out_ij = a_ij * u_i * v_j (a already 0 outside block) ----
    float ur[16], vr[16];
    #pragma unroll
    for (int k = 0; k < 16; ++k) ur[k] = sh_u[tr + 32*k];
    #pragma unroll
    for (int q = 0; q < 4; ++q) {
        float4 v4 = *(const float4*)&sh_v[c0 + 4*q];
        vr[4*q+0] = v4.x; vr[4*q+1] = v4.y; vr[4*q+2] = v4.z; vr[4*q+3] = v4.w;
    }
    float* ob = out + (size_t)b * (MM * NN);
    #pragma unroll
    for (int k = 0; k < 16; ++k) {
        const int r = tr + 32 * k;
        float4* rp = (float4*)(ob + (size_t)r * NN + c0);
        #pragma unroll
        for (int q = 0; q < 4; ++q) {
            float4 o;
            o.x = a[k][4*q+0] * ur[k] * vr[4*q+0];
            o.y = a[k][4*q+1] * ur[k] * vr[4*q+1];
            o.z = a[k][4*q+2] * ur[k] * vr[4*q+2];
            o.w = a[k][4*q+3] * ur[k] * vr[4*q+3];
            rp[q] = o;
        }
    }
}

extern "C" void kernel_launch(void* const* d_in, const int* in_sizes, int n_in,
                              void* d_out, int out_size, void* d_ws, size_t ws_size,
                              hipStream_t stream) {
    const float* s     = (const float*)d_in[0];
    const int*   nrows = (const int*)d_in[1];
    const int*   ncols = (const int*)d_in[2];
    float*       out   = (float*)d_out;
    const int B = in_sizes[1];   // 256 batches, one block (one CU) each
    sinkhorn_kernel<<<dim3(B), dim3(1024), 0, stream>>>(s, nrows, ncols, out);
}

// Round 2
// 1233.986 us; speedup vs baseline: 1.2393x; 1.2393x over previous
//
#include <hip/hip_runtime.h>

// Sinkhorn-Knopp, factored: s_ij = a_ij * u_i * v_j throughout.
// One 1024-thread block per batch; the 512x512 fp32 matrix lives in VGPRs as
// 16 *named* ext_vector_type(16) values per thread (A0..A15) — named SSA
// vectors, NOT an alloca'd array: round 1 proved float a[16][16] stays in
// scratch (VGPR_Count=64, 2.9 GB HBM traffic). All element indices are
// preprocessor constants so every access is extract/insertelement.
// Thread (tr=tid&31, tc=tid>>5) owns rows {tr+32k} (row%32==lane =>
// conflict-free LDS scatter) and cols [16*tc,16*tc+16) (contiguous loads).
#define MM 512
#define NN 512
#define NITER 20
#define SEPS 1e-10f

typedef float f16v __attribute__((ext_vector_type(16)));

#define RPT16(F) F(0) F(1) F(2) F(3) F(4) F(5) F(6) F(7) F(8) F(9) F(10) F(11) F(12) F(13) F(14) F(15)
#define RPT15(F) F(1) F(2) F(3) F(4) F(5) F(6) F(7) F(8) F(9) F(10) F(11) F(12) F(13) F(14) F(15)

// Load 16 floats from sh_v[c0..c0+15] into a named f16v via float4 reads.
#define LOADVR(v) f16v v; { \
    const float4* vp__ = (const float4*)&sh_v[c0]; \
    float4 x0 = vp__[0], x1 = vp__[1], x2 = vp__[2], x3 = vp__[3]; \
    v[0]=x0.x;  v[1]=x0.y;  v[2]=x0.z;  v[3]=x0.w; \
    v[4]=x1.x;  v[5]=x1.y;  v[6]=x1.z;  v[7]=x1.w; \
    v[8]=x2.x;  v[9]=x2.y;  v[10]=x2.z; v[11]=x2.w; \
    v[12]=x3.x; v[13]=x3.y; v[14]=x3.z; v[15]=x3.w; }

__global__ __launch_bounds__(1024, 4) void sinkhorn_kernel(
    const float* __restrict__ s, const int* __restrict__ nrows,
    const int* __restrict__ ncols, float* __restrict__ out)
{
    __shared__ float sh_u[512];
    __shared__ float sh_v[512];
    __shared__ float red[16][513];   // stride 513 => bank = (h + idx) % 32

    const int b   = blockIdx.x;
    const int tid = threadIdx.x;
    const int tr  = tid & 31;        // row lane: owns rows tr + 32k
    const int tc  = tid >> 5;        // col tile: owns cols [16*tc, 16*tc+16)
    const int c0  = tc * 16;

    const int nr = nrows[b];
    const int nc = ncols[b];

    if (tid < 512) sh_u[tid] = 1.0f;

    // Column mask (multiplicative; inputs are finite uniforms so 0*x == 0).
    f16v cmask;
#define CMEL(e) cmask[e] = ((c0 + (e)) < nc) ? 1.0f : 0.0f;
    RPT16(CMEL)

#define DECLA(k) f16v A##k;
    RPT16(DECLA)

    // ---- load + mask: A = (s0 + EPS) * rowmask * colmask ----
    const float* sb = s + (size_t)b * (MM * NN);
#define LOADK(k) { \
        const int r__ = tr + 32*(k); \
        const float rm__ = (r__ < nr) ? 1.0f : 0.0f; \
        const float4* rp__ = (const float4*)(sb + (size_t)r__ * NN + c0); \
        float4 w0 = rp__[0], w1 = rp__[1], w2 = rp__[2], w3 = rp__[3]; \
        f16v t__; \
        t__[0]=w0.x;  t__[1]=w0.y;  t__[2]=w0.z;  t__[3]=w0.w; \
        t__[4]=w1.x;  t__[5]=w1.y;  t__[6]=w1.z;  t__[7]=w1.w; \
        t__[8]=w2.x;  t__[9]=w2.y;  t__[10]=w2.z; t__[11]=w2.w; \
        t__[12]=w3.x; t__[13]=w3.y; t__[14]=w3.z; t__[15]=w3.w; \
        A##k = (t__ + SEPS) * (cmask * rm__); \
    }
    RPT16(LOADK)
    __syncthreads();   // sh_u init visible

#pragma unroll 1
    for (int it = 0; it < NITER / 2; ++it) {
        { // ---- even iter: col sums c_j = sum_i a_ij u_i ; v_j = 1/c_j ----
#define LDU(k) const float ur##k = sh_u[tr + 32*(k)];
            RPT16(LDU)
            f16v accv = A0 * ur0;
#define ACCK(k) accv += A##k * ur##k;
            RPT15(ACCK)
#define COLJ(j) { float a__ = accv[j]; a__ += __shfl_xor(a__, 16); \
                  if ((tid & 16) == 0) red[tr & 15][c0 + (j)] = a__; }
            RPT16(COLJ)
        }
        __syncthreads();
        if (tid < 512) {
            float ssum = 0.0f;
            #pragma unroll
            for (int h = 0; h < 16; ++h) ssum += red[h][tid];
            sh_v[tid] = (ssum > 0.0f) ? 1.0f / ssum : 1.0f;
        }
        __syncthreads();

        { // ---- odd iter: row sums r_i = sum_j a_ij v_j ; u_i = 1/r_i ----
            LOADVR(vrv)
#define ROWK(k) { f16v t__ = A##k * vrv; \
        float a__ = (((t__[0]+t__[1])+(t__[2]+t__[3])) + ((t__[4]+t__[5])+(t__[6]+t__[7]))) \
                  + (((t__[8]+t__[9])+(t__[10]+t__[11])) + ((t__[12]+t__[13])+(t__[14]+t__[15]))); \
        a__ += __shfl_xor(a__, 32); \
        if ((tid & 32) == 0) red[tc >> 1][tr + 32*(k)] = a__; }
            RPT16(ROWK)
        }
        __syncthreads();
        if (tid < 512) {
            float ssum = 0.0f;
            #pragma unroll
            for (int h = 0; h < 16; ++h) ssum += red[h][tid];
            sh_u[tid] = (ssum > 0.0f) ? 1.0f / ssum : 1.0f;
        }
        __syncthreads();
    }

    // ---- epilogue: out = A * u * v (A already 0 outside valid block) ----
    LOADVR(vrf)
#define LDUF(k) const float uf##k = sh_u[tr + 32*(k)];
    RPT16(LDUF)
    float* ob = out + (size_t)b * (MM * NN);
#define STK(k) { \
        const int r__ = tr + 32*(k); \
        f16v o__ = A##k * (vrf * uf##k); \
        float4* op__ = (float4*)(ob + (size_t)r__ * NN + c0); \
        float4 w__; \
        w__.x=o__[0];  w__.y=o__[1];  w__.z=o__[2];  w__.w=o__[3];  op__[0] = w__; \
        w__.x=o__[4];  w__.y=o__[5];  w__.z=o__[6];  w__.w=o__[7];  op__[1] = w__; \
        w__.x=o__[8];  w__.y=o__[9];  w__.z=o__[10]; w__.w=o__[11]; op__[2] = w__; \
        w__.x=o__[12]; w__.y=o__[13]; w__.z=o__[14]; w__.w=o__[15]; op__[3] = w__; \
    }
    RPT16(STK)
}

extern "C" void kernel_launch(void* const* d_in, const int* in_sizes, int n_in,
                              void* d_out, int out_size, void* d_ws, size_t ws_size,
                              hipStream_t stream) {
    const float* s     = (const float*)d_in[0];
    const int*   nrows = (const int*)d_in[1];
    const int*   ncols = (const int*)d_in[2];
    float*       out   = (float*)d_out;
    const int B = in_sizes[1];   // 256 batches, one block (one CU) each
    sinkhorn_kernel<<<dim3(B), dim3(1024), 0, stream>>>(s, nrows, ncols, out);
}

// Round 3
// 1053.508 us; speedup vs baseline: 1.4516x; 1.1713x over previous
//
#include <hip/hip_runtime.h>

// Sinkhorn-Knopp, factored: s_ij = a_ij * u_i * v_j; only u,v evolve.
// Round-2 lesson: per-SIMD VGPR pool = 512. 1024-thr blocks cap waves at
// 128 VGPR -> full spill. Fix: 512-thr blocks (2 waves/SIMD -> 256 VGPR cap)
// + bf16 storage (matrix 512 KB/batch): 12/16 rows in named packed regs
// (192 VGPR), 4/16 rows in XOR-swizzled LDS (128 KB), conflict-free b128.
// Thread (tr=tid&31, tc=tid>>5) owns rows {tr+32k, k<16}, cols [32tc,32tc+32).
// Col j reduction: 32-lane shuffle tree (cols of one tc-group live in one
// half-wave); final col id == tid. Row reduction: shfl_xor(32) + red[8][...].
#define SEPS 1e-10f

typedef unsigned int uu;
typedef uu v16u __attribute__((ext_vector_type(16)));

#define RPTK12(F) F(0) F(1) F(2) F(3) F(4) F(5) F(6) F(7) F(8) F(9) F(10) F(11)

__device__ __forceinline__ uu bfpack2(float f0, float f1) {
    uu u0 = __float_as_uint(f0 + SEPS);
    uu u1 = __float_as_uint(f1 + SEPS);
    u0 += 0x7FFFu + ((u0 >> 16) & 1u);   // RNE to bf16
    u1 += 0x7FFFu + ((u1 >> 16) & 1u);
    return (u0 >> 16) | (u1 & 0xFFFF0000u);  // low16 = even col, high16 = odd col
}

__global__
__attribute__((amdgpu_flat_work_group_size(512, 512)))
__attribute__((amdgpu_waves_per_eu(2)))
void sinkhorn_kernel(const float* __restrict__ s, const int* __restrict__ nrows,
                     const int* __restrict__ ncols, float* __restrict__ out)
{
    __shared__ uu    spill[512 * 64];   // 128 KB: 4 rows x 32 cols (bf16) per thread
    __shared__ float sh_u[512];
    __shared__ float sh_v[512];
    __shared__ float red[8][516];       // 16.1 KB; stride 516 breaks bank alignment

    const int b   = blockIdx.x;
    const int tid = threadIdx.x;
    const int tr  = tid & 31;
    const int tc  = tid >> 5;
    const int c0  = tc << 5;
    const int wv  = tid >> 6;
    const int nr  = nrows[b];
    const int nc  = ncols[b];
    const bool cact = (c0 < nc);
    uu* sp = spill + tid * 64;          // 256 B private LDS block

    sh_u[tid] = 1.0f;

    // column-pair bitmasks (bf16 pair packed in one u32)
#define CMASK(h) const uu m##h = (nc >= c0 + 2*(h) + 2) ? 0xFFFFFFFFu : ((nc == c0 + 2*(h) + 1) ? 0x0000FFFFu : 0u);
    CMASK(0) CMASK(1) CMASK(2) CMASK(3) CMASK(4) CMASK(5) CMASK(6) CMASK(7)
    CMASK(8) CMASK(9) CMASK(10) CMASK(11) CMASK(12) CMASK(13) CMASK(14) CMASK(15)

#define DECLR(k) v16u R##k;
    RPTK12(DECLR)

    const float* sb = s + ((size_t)b << 18);

#define LOADROW(PDST, k) { \
    const int r__ = tr + 32*(k); \
    const uu rm__ = (r__ < nr) ? 0xFFFFFFFFu : 0u; \
    const float4* rp__ = (const float4*)(sb + ((size_t)r__ << 9) + c0); \
    float4 w0 = rp__[0], w1 = rp__[1], w2 = rp__[2], w3 = rp__[3]; \
    float4 w4 = rp__[4], w5 = rp__[5], w6 = rp__[6], w7 = rp__[7]; \
    PDST[0]  = bfpack2(w0.x, w0.y) & m0  & rm__; \
    PDST[1]  = bfpack2(w0.z, w0.w) & m1  & rm__; \
    PDST[2]  = bfpack2(w1.x, w1.y) & m2  & rm__; \
    PDST[3]  = bfpack2(w1.z, w1.w) & m3  & rm__; \
    PDST[4]  = bfpack2(w2.x, w2.y) & m4  & rm__; \
    PDST[5]  = bfpack2(w2.z, w2.w) & m5  & rm__; \
    PDST[6]  = bfpack2(w3.x, w3.y) & m6  & rm__; \
    PDST[7]  = bfpack2(w3.z, w3.w) & m7  & rm__; \
    PDST[8]  = bfpack2(w4.x, w4.y) & m8  & rm__; \
    PDST[9]  = bfpack2(w4.z, w4.w) & m9  & rm__; \
    PDST[10] = bfpack2(w5.x, w5.y) & m10 & rm__; \
    PDST[11] = bfpack2(w5.z, w5.w) & m11 & rm__; \
    PDST[12] = bfpack2(w6.x, w6.y) & m12 & rm__; \
    PDST[13] = bfpack2(w6.z, w6.w) & m13 & rm__; \
    PDST[14] = bfpack2(w7.x, w7.y) & m14 & rm__; \
    PDST[15] = bfpack2(w7.z, w7.w) & m15 & rm__; }

#define LOADK(k) if (32*(k) < nr && cact) { LOADROW(R##k, k) } \
    __builtin_amdgcn_sched_barrier(0);
    RPTK12(LOADK)

#define SPADDR(k, q) (sp + ((((((k)-12)<<2) + (q)) ^ (tid & 15)) << 2))
#define LOADLDSK(k) if (32*(k) < nr && cact) { \
    v16u T__; LOADROW(T__, k) \
    *(uint4*)SPADDR(k,0) = make_uint4(T__[0],  T__[1],  T__[2],  T__[3]); \
    *(uint4*)SPADDR(k,1) = make_uint4(T__[4],  T__[5],  T__[6],  T__[7]); \
    *(uint4*)SPADDR(k,2) = make_uint4(T__[8],  T__[9],  T__[10], T__[11]); \
    *(uint4*)SPADDR(k,3) = make_uint4(T__[12], T__[13], T__[14], T__[15]); } \
    __builtin_amdgcn_sched_barrier(0);
    LOADLDSK(12) LOADLDSK(13) LOADLDSK(14) LOADLDSK(15)

    __syncthreads();   // spill + sh_u visible

#define UFW(w, uk, A, B) { const uu w__ = (w); \
    A += __uint_as_float(w__ << 16) * (uk); \
    B += __uint_as_float(w__ & 0xFFFF0000u) * (uk); }

#define COLBODY(P, uk) \
    UFW(P[0],  uk, ca0,  ca1)  UFW(P[1],  uk, ca2,  ca3) \
    UFW(P[2],  uk, ca4,  ca5)  UFW(P[3],  uk, ca6,  ca7) \
    UFW(P[4],  uk, ca8,  ca9)  UFW(P[5],  uk, ca10, ca11) \
    UFW(P[6],  uk, ca12, ca13) UFW(P[7],  uk, ca14, ca15) \
    UFW(P[8],  uk, ca16, ca17) UFW(P[9],  uk, ca18, ca19) \
    UFW(P[10], uk, ca20, ca21) UFW(P[11], uk, ca22, ca23) \
    UFW(P[12], uk, ca24, ca25) UFW(P[13], uk, ca26, ca27) \
    UFW(P[14], uk, ca28, ca29) UFW(P[15], uk, ca30, ca31)

#define COLK(k) if (32*(k) < nr && cact) { \
    const float uk__ = sh_u[tr + 32*(k)]; \
    COLBODY(R##k, uk__) }

#define COLLDSQ(k, q, A0,A1,A2,A3,A4,A5,A6,A7) { \
    uint4 t__ = *(const uint4*)SPADDR(k,q); \
    UFW(t__.x, uk__, A0, A1) UFW(t__.y, uk__, A2, A3) \
    UFW(t__.z, uk__, A4, A5) UFW(t__.w, uk__, A6, A7) }

#define COLLDS(k) if (32*(k) < nr && cact) { \
    const float uk__ = sh_u[tr + 32*(k)]; \
    COLLDSQ(k,0, ca0,ca1,ca2,ca3,ca4,ca5,ca6,ca7) \
    COLLDSQ(k,1, ca8,ca9,ca10,ca11,ca12,ca13,ca14,ca15) \
    COLLDSQ(k,2, ca16,ca17,ca18,ca19,ca20,ca21,ca22,ca23) \
    COLLDSQ(k,3, ca24,ca25,ca26,ca27,ca28,ca29,ca30,ca31) }

    // shuffle-tree stage: keep cols matching own lane bit, add partner's
#define TST(m, OUT, A0, A1) float OUT; { \
    const float t0__ = __shfl_xor(A0, m); \
    const float t1__ = __shfl_xor(A1, m); \
    OUT = (tid & (m)) ? ((A1) + t1__) : ((A0) + t0__); }

#define RWH(w, VA, VB) { const uu w__ = (w); \
    acc__ += __uint_as_float(w__ << 16) * (VA); \
    acc__ += __uint_as_float(w__ & 0xFFFF0000u) * (VB); }

#define ROWBODY(P) \
    RWH(P[0],  vz0.x, vz0.y) RWH(P[1],  vz0.z, vz0.w) \
    RWH(P[2],  vz1.x, vz1.y) RWH(P[3],  vz1.z, vz1.w) \
    RWH(P[4],  vz2.x, vz2.y) RWH(P[5],  vz2.z, vz2.w) \
    RWH(P[6],  vz3.x, vz3.y) RWH(P[7],  vz3.z, vz3.w) \
    RWH(P[8],  vz4.x, vz4.y) RWH(P[9],  vz4.z, vz4.w) \
    RWH(P[10], vz5.x, vz5.y) RWH(P[11], vz5.z, vz5.w) \
    RWH(P[12], vz6.x, vz6.y) RWH(P[13], vz6.z, vz6.w) \
    RWH(P[14], vz7.x, vz7.y) RWH(P[15], vz7.z, vz7.w)

#define ROWK(k) { float acc__ = 0.0f; \
    if (32*(k) < nr && cact) { ROWBODY(R##k) } \
    acc__ += __shfl_xor(acc__, 32); \
    if ((tid & 32) == 0) red[wv][tr + 32*(k)] = acc__; }

#define ROWLDSQ(k,q, VA0,VB0,VA1,VB1,VA2,VB2,VA3,VB3) { \
    uint4 t__ = *(const uint4*)SPADDR(k,q); \
    RWH(t__.x, VA0, VB0) RWH(t__.y, VA1, VB1) \
    RWH(t__.z, VA2, VB2) RWH(t__.w, VA3, VB3) }

#define ROWLDSK(k) { float acc__ = 0.0f; \
    if (32*(k) < nr && cact) { \
      ROWLDSQ(k,0, vz0.x,vz0.y, vz0.z,vz0.w, vz1.x,vz1.y, vz1.z,vz1.w) \
      ROWLDSQ(k,1, vz2.x,vz2.y, vz2.z,vz2.w, vz3.x,vz3.y, vz3.z,vz3.w) \
      ROWLDSQ(k,2, vz4.x,vz4.y, vz4.z,vz4.w, vz5.x,vz5.y, vz5.z,vz5.w) \
      ROWLDSQ(k,3, vz6.x,vz6.y, vz6.z,vz6.w, vz7.x,vz7.y, vz7.z,vz7.w) } \
    acc__ += __shfl_xor(acc__, 32); \
    if ((tid & 32) == 0) red[wv][tr + 32*(k)] = acc__; }

#pragma unroll 1
    for (int it = 0; it < 10; ++it) {
        // ---- col pass: c_j = sum_i a_ij u_i (cols of one tc live in one half-wave)
        float ca0=0.0f,ca1=0.0f,ca2=0.0f,ca3=0.0f,ca4=0.0f,ca5=0.0f,ca6=0.0f,ca7=0.0f,
              ca8=0.0f,ca9=0.0f,ca10=0.0f,ca11=0.0f,ca12=0.0f,ca13=0.0f,ca14=0.0f,ca15=0.0f,
              ca16=0.0f,ca17=0.0f,ca18=0.0f,ca19=0.0f,ca20=0.0f,ca21=0.0f,ca22=0.0f,ca23=0.0f,
              ca24=0.0f,ca25=0.0f,ca26=0.0f,ca27=0.0f,ca28=0.0f,ca29=0.0f,ca30=0.0f,ca31=0.0f;
        RPTK12(COLK)
        COLLDS(12) COLLDS(13) COLLDS(14) COLLDS(15)
        // 32-lane tree; all lanes participate (accs are 0 where masked)
        TST(1, d0,  ca0,  ca1)  TST(1, d1,  ca2,  ca3)  TST(1, d2,  ca4,  ca5)  TST(1, d3,  ca6,  ca7)
        TST(1, d4,  ca8,  ca9)  TST(1, d5,  ca10, ca11) TST(1, d6,  ca12, ca13) TST(1, d7,  ca14, ca15)
        TST(1, d8,  ca16, ca17) TST(1, d9,  ca18, ca19) TST(1, d10, ca20, ca21) TST(1, d11, ca22, ca23)
        TST(1, d12, ca24, ca25) TST(1, d13, ca26, ca27) TST(1, d14, ca28, ca29) TST(1, d15, ca30, ca31)
        TST(2, e0, d0, d1)   TST(2, e1, d2, d3)   TST(2, e2, d4, d5)   TST(2, e3, d6, d7)
        TST(2, e4, d8, d9)   TST(2, e5, d10, d11) TST(2, e6, d12, d13) TST(2, e7, d14, d15)
        TST(4, f0, e0, e1) TST(4, f1, e2, e3) TST(4, f2, e4, e5) TST(4, f3, e6, e7)
        TST(8, g0, f0, f1) TST(8, g1, f2, f3)
        TST(16, h0, g0, g1)
        // final col id == tid; write v_j
        sh_v[tid] = (h0 > 0.0f) ? 1.0f / h0 : 1.0f;
        __syncthreads();

        // ---- row pass: r_i = sum_j a_ij v_j
        float4 vz0 = *(const float4*)&sh_v[c0 +  0];
        float4 vz1 = *(const float4*)&sh_v[c0 +  4];
        float4 vz2 = *(const float4*)&sh_v[c0 +  8];
        float4 vz3 = *(const float4*)&sh_v[c0 + 12];
        float4 vz4 = *(const float4*)&sh_v[c0 + 16];
        float4 vz5 = *(const float4*)&sh_v[c0 + 20];
        float4 vz6 = *(const float4*)&sh_v[c0 + 24];
        float4 vz7 = *(const float4*)&sh_v[c0 + 28];
        RPTK12(ROWK)
        ROWLDSK(12) ROWLDSK(13) ROWLDSK(14) ROWLDSK(15)
        __syncthreads();
        {   // u_i = 1 / sum of 8 wave-partials; row id == tid
            float ss = red[0][tid] + red[1][tid] + red[2][tid] + red[3][tid]
                     + red[4][tid] + red[5][tid] + red[6][tid] + red[7][tid];
            sh_u[tid] = (ss > 0.0f) ? 1.0f / ss : 1.0f;
        }
        __syncthreads();
    }

    // ---- epilogue: out = a * u_i * v_j  (a==0 outside valid block)
    float4 vz0 = *(const float4*)&sh_v[c0 +  0];
    float4 vz1 = *(const float4*)&sh_v[c0 +  4];
    float4 vz2 = *(const float4*)&sh_v[c0 +  8];
    float4 vz3 = *(const float4*)&sh_v[c0 + 12];
    float4 vz4 = *(const float4*)&sh_v[c0 + 16];
    float4 vz5 = *(const float4*)&sh_v[c0 + 20];
    float4 vz6 = *(const float4*)&sh_v[c0 + 24];
    float4 vz7 = *(const float4*)&sh_v[c0 + 28];
    float* ob = out + ((size_t)b << 18);

#define EPW(w, UK, VA, VB, OX, OY) { const uu w__ = (w); \
    OX = __uint_as_float(w__ << 16) * (UK) * (VA); \
    OY = __uint_as_float(w__ & 0xFFFF0000u) * (UK) * (VB); }

#define STK(k) { \
    float4* op__ = (float4*)(ob + ((size_t)(tr + 32*(k)) << 9) + c0); \
    if (32*(k) < nr && cact) { \
      const float uk__ = sh_u[tr + 32*(k)]; float4 o__; \
      EPW(R##k[0],  uk__, vz0.x, vz0.y, o__.x, o__.y) EPW(R##k[1],  uk__, vz0.z, vz0.w, o__.z, o__.w) op__[0] = o__; \
      EPW(R##k[2],  uk__, vz1.x, vz1.y, o__.x, o__.y) EPW(R##k[3],  uk__, vz1.z, vz1.w, o__.z, o__.w) op__[1] = o__; \
      EPW(R##k[4],  uk__, vz2.x, vz2.y, o__.x, o__.y) EPW(R##k[5],  uk__, vz2.z, vz2.w, o__.z, o__.w) op__[2] = o__; \
      EPW(R##k[6],  uk__, vz3.x, vz3.y, o__.x, o__.y) EPW(R##k[7],  uk__, vz3.z, vz3.w, o__.z, o__.w) op__[3] = o__; \
      EPW(R##k[8],  uk__, vz4.x, vz4.y, o__.x, o__.y) EPW(R##k[9],  uk__, vz4.z, vz4.w, o__.z, o__.w) op__[4] = o__; \
      EPW(R##k[10], uk__, vz5.x, vz5.y, o__.x, o__.y) EPW(R##k[11], uk__, vz5.z, vz5.w, o__.z, o__.w) op__[5] = o__; \
      EPW(R##k[12], uk__, vz6.x, vz6.y, o__.x, o__.y) EPW(R##k[13], uk__, vz6.z, vz6.w, o__.z, o__.w) op__[6] = o__; \
      EPW(R##k[14], uk__, vz7.x, vz7.y, o__.x, o__.y) EPW(R##k[15], uk__, vz7.z, vz7.w, o__.z, o__.w) op__[7] = o__; \
    } else { \
      const float4 z__ = make_float4(0.f,0.f,0.f,0.f); \
      op__[0]=z__; op__[1]=z__; op__[2]=z__; op__[3]=z__; \
      op__[4]=z__; op__[5]=z__; op__[6]=z__; op__[7]=z__; } } \
    __builtin_amdgcn_sched_barrier(0);
    RPTK12(STK)

#define STLDSK(k) { \
    float4* op__ = (float4*)(ob + ((size_t)(tr + 32*(k)) << 9) + c0); \
    if (32*(k) < nr && cact) { \
      const float uk__ = sh_u[tr + 32*(k)]; float4 o__; \
      uint4 q0__ = *(const uint4*)SPADDR(k,0); \
      uint4 q1__ = *(const uint4*)SPADDR(k,1); \
      uint4 q2__ = *(const uint4*)SPADDR(k,2); \
      uint4 q3__ = *(const uint4*)SPADDR(k,3); \
      EPW(q0__.x, uk__, vz0.x, vz0.y, o__.x, o__.y) EPW(q0__.y, uk__, vz0.z, vz0.w, o__.z, o__.w) op__[0] = o__; \
      EPW(q0__.z, uk__, vz1.x, vz1.y, o__.x, o__.y) EPW(q0__.w, uk__, vz1.z, vz1.w, o__.z, o__.w) op__[1] = o__; \
      EPW(q1__.x, uk__, vz2.x, vz2.y, o__.x, o__.y) EPW(q1__.y, uk__, vz2.z, vz2.w, o__.z, o__.w) op__[2] = o__; \
      EPW(q1__.z, uk__, vz3.x, vz3.y, o__.x, o__.y) EPW(q1__.w, uk__, vz3.z, vz3.w, o__.z, o__.w) op__[3] = o__; \
      EPW(q2__.x, uk__, vz4.x, vz4.y, o__.x, o__.y) EPW(q2__.y, uk__, vz4.z, vz4.w, o__.z, o__.w) op__[4] = o__; \
      EPW(q2__.z, uk__, vz5.x, vz5.y, o__.x, o__.y) EPW(q2__.w, uk__, vz5.z, vz5.w, o__.z, o__.w) op__[5] = o__; \
      EPW(q3__.x, uk__, vz6.x, vz6.y, o__.x, o__.y) EPW(q3__.y, uk__, vz6.z, vz6.w, o__.z, o__.w) op__[6] = o__; \
      EPW(q3__.z, uk__, vz7.x, vz7.y, o__.x, o__.y) EPW(q3__.w, uk__, vz7.z, vz7.w, o__.z, o__.w) op__[7] = o__; \
    } else { \
      const float4 z__ = make_float4(0.f,0.f,0.f,0.f); \
      op__[0]=z__; op__[1]=z__; op__[2]=z__; op__[3]=z__; \
      op__[4]=z__; op__[5]=z__; op__[6]=z__; op__[7]=z__; } } \
    __builtin_amdgcn_sched_barrier(0);
    STLDSK(12) STLDSK(13) STLDSK(14) STLDSK(15)
}

extern "C" void kernel_launch(void* const* d_in, const int* in_sizes, int n_in,
                              void* d_out, int out_size, void* d_ws, size_t ws_size,
                              hipStream_t stream) {
    const float* s     = (const float*)d_in[0];
    const int*   nrows = (const int*)d_in[1];
    const int*   ncols = (const int*)d_in[2];
    float*       out   = (float*)d_out;
    const int B = in_sizes[1];   // 256 batches, one 512-thread block (one CU) each
    sinkhorn_kernel<<<dim3(B), dim3(512), 0, stream>>>(s, nrows, ncols, out);
}